// Round 1
// baseline (2827.146 us; speedup 1.0000x reference)
//
#include <hip/hip_runtime.h>
#include <stdint.h>
#include <stddef.h>

#define S_LEN 2048
#define BATCH 32
#define NIN   256
#define NH    256
#define NG    768   // 3*NH

typedef _Float16 half2_t __attribute__((ext_vector_type(2)));
typedef _Float16 half8_t __attribute__((ext_vector_type(8)));
typedef int      int16v  __attribute__((ext_vector_type(16)));

#if __has_builtin(__builtin_amdgcn_exp2f)
#define EXP2F(x) __builtin_amdgcn_exp2f(x)
#else
#define EXP2F(x) exp2f(x)
#endif

static __device__ __forceinline__ float fdot2(half2_t a, half2_t b, float c) {
  return __builtin_amdgcn_fdot2(a, b, c, false);
}
static __device__ __forceinline__ half2_t pack2(float lo, float hi) {
  half2_t r; r[0] = (_Float16)lo; r[1] = (_Float16)hi; return r;
}
static __device__ __forceinline__ float sigmoid_fast(float x) {
  float e = EXP2F(-1.44269504088896340736f * x);
  return 1.0f / (1.0f + e);
}
static __device__ __forceinline__ float tanh_fast(float x) {
  float e = EXP2F(2.88539008177792681472f * x);
  return 1.0f - 2.0f / (1.0f + e);
}

// bit-cast helpers: element extracts use LITERAL indices -> pure SSA, no allocas
#define BH(x)    __builtin_bit_cast(half2_t, (x))
#define BW(W, e) __builtin_bit_cast(half2_t, (int)((W)[e]))

// ---- xproj path (unchanged): LDS/VGPR h lines vs weight vector ----
#define DOT16(W, i0) do {                                                     \
    int4 q0 = hls[(i0) + 0], q1 = hls[(i0) + 1];                              \
    int4 q2 = hls[(i0) + 2], q3 = hls[(i0) + 3];                              \
    a0 = fdot2(BH(q0.x), BW(W, 0),  a0); a1 = fdot2(BH(q0.y), BW(W, 1),  a1);\
    a2 = fdot2(BH(q0.z), BW(W, 2),  a2); a3 = fdot2(BH(q0.w), BW(W, 3),  a3);\
    a0 = fdot2(BH(q1.x), BW(W, 4),  a0); a1 = fdot2(BH(q1.y), BW(W, 5),  a1);\
    a2 = fdot2(BH(q1.z), BW(W, 6),  a2); a3 = fdot2(BH(q1.w), BW(W, 7),  a3);\
    a0 = fdot2(BH(q2.x), BW(W, 8),  a0); a1 = fdot2(BH(q2.y), BW(W, 9),  a1);\
    a2 = fdot2(BH(q2.z), BW(W, 10), a2); a3 = fdot2(BH(q2.w), BW(W, 11), a3);\
    a0 = fdot2(BH(q3.x), BW(W, 12), a0); a1 = fdot2(BH(q3.y), BW(W, 13), a1);\
    a2 = fdot2(BH(q3.z), BW(W, 14), a2); a3 = fdot2(BH(q3.w), BW(W, 15), a3);\
  } while (0)

// ---- gru path: h chunk held in SGPRs (wave-shared broadcast, zero LDS traffic) ----
// same accumulator rotation as DOT16 -> bit-identical sums
#define DOTS(HS, W) do {                                                      \
    a0 = fdot2(BW(HS, 0),  BW(W, 0),  a0); a1 = fdot2(BW(HS, 1),  BW(W, 1),  a1);\
    a2 = fdot2(BW(HS, 2),  BW(W, 2),  a2); a3 = fdot2(BW(HS, 3),  BW(W, 3),  a3);\
    a0 = fdot2(BW(HS, 4),  BW(W, 4),  a0); a1 = fdot2(BW(HS, 5),  BW(W, 5),  a1);\
    a2 = fdot2(BW(HS, 6),  BW(W, 6),  a2); a3 = fdot2(BW(HS, 7),  BW(W, 7),  a3);\
    a0 = fdot2(BW(HS, 8),  BW(W, 8),  a0); a1 = fdot2(BW(HS, 9),  BW(W, 9),  a1);\
    a2 = fdot2(BW(HS, 10), BW(W, 10), a2); a3 = fdot2(BW(HS, 11), BW(W, 11), a3);\
    a0 = fdot2(BW(HS, 12), BW(W, 12), a0); a1 = fdot2(BW(HS, 13), BW(W, 13), a1);\
    a2 = fdot2(BW(HS, 14), BW(W, 14), a2); a3 = fdot2(BW(HS, 15), BW(W, 15), a3);\
  } while (0)

#define LDW(W, o) do {                                                        \
    int4 q0 = wsrc[(o) + 0], q1 = wsrc[(o) + 1];                              \
    int4 q2 = wsrc[(o) + 2], q3 = wsrc[(o) + 3];                              \
    W = (int16v){q0.x, q0.y, q0.z, q0.w, q1.x, q1.y, q1.z, q1.w,              \
                 q2.x, q2.y, q2.z, q2.w, q3.x, q3.y, q3.z, q3.w};             \
  } while (0)

// scalar load of one 16-dword (32 f16) h chunk; offset must be a literal string.
// SMEM returns can be out-of-order -> only lgkmcnt(0) waits, with the loaded
// values tied through the wait asm ("+s") so consumers cannot be hoisted past it.
#define SLOAD(dst, base, off) \
  asm volatile("s_load_dwordx16 %0, %1, " off : "=s"(dst) : "s"(base))
#define SWAIT1(a)       asm volatile("s_waitcnt lgkmcnt(0)" : "+s"(a))
#define SWAIT2(a, b)    asm volatile("s_waitcnt lgkmcnt(0)" : "+s"(a), "+s"(b))
#define SWAIT3(a, b, c) asm volatile("s_waitcnt lgkmcnt(0)" : "+s"(a), "+s"(b), "+s"(c))

// ---------------- prep: input f32 -> f16 ----------------
__global__ __launch_bounds__(256) void prep_in_kernel(const float* __restrict__ in,
                                                      _Float16* __restrict__ in16) {
  size_t v = (size_t)blockIdx.x * 256 + threadIdx.x;
  const float4* p4 = (const float4*)in;
  float4 a = p4[v * 2 + 0];
  float4 b = p4[v * 2 + 1];
  half8_t o;
  o[0] = (_Float16)a.x; o[1] = (_Float16)a.y; o[2] = (_Float16)a.z; o[3] = (_Float16)a.w;
  o[4] = (_Float16)b.x; o[5] = (_Float16)b.y; o[6] = (_Float16)b.z; o[7] = (_Float16)b.w;
  ((half8_t*)in16)[v] = o;
}

// ---------------- prep: weights pack to f16 pairs + bias ----------------
__global__ __launch_bounds__(256) void prep_w_kernel(const float* __restrict__ W_ih,
                                                     const float* __restrict__ W_hh,
                                                     const float* __restrict__ b_ih,
                                                     const float* __restrict__ b_hh,
                                                     half2_t* __restrict__ whh2g,
                                                     half2_t* __restrict__ wih2,
                                                     float* __restrict__ bias) {
  int idx = blockIdx.x * 256 + threadIdx.x;
  if (idx < 128 * NG) {
    int g = idx >> 7, kk = idx & 127;
    whh2g[idx] = pack2(W_hh[(size_t)g * NH + 2 * kk], W_hh[(size_t)g * NH + 2 * kk + 1]);
  } else if (idx < 2 * 128 * NG) {
    int i2 = idx - 128 * NG;
    int g = i2 >> 7, kk = i2 & 127;
    wih2[(size_t)g * 128 + kk] = pack2(W_ih[(size_t)g * NIN + 2 * kk], W_ih[(size_t)g * NIN + 2 * kk + 1]);
  } else if (idx < 2 * 128 * NG + NG) {
    int g = idx - 2 * 128 * NG;
    bias[g] = b_ih[g] + b_hh[g];
  }
}

// ---------------- x_proj GEMM (unchanged) ----------------
__global__
__attribute__((amdgpu_flat_work_group_size(768, 768), amdgpu_waves_per_eu(3, 3)))
void xproj_kernel(const _Float16* __restrict__ in16,
                  const half2_t* __restrict__ wih2,
                  const float* __restrict__ bias,
                  float* __restrict__ xp_out) {
  __shared__ char occ_pad[86016];
  {
    unsigned lp = (unsigned)(uintptr_t)&occ_pad[0];
    asm volatile("" :: "v"(lp));
  }
  const int g = threadIdx.x;
  const int row0 = blockIdx.x * 64;
  const float bg = bias[g];

  int16v w0, w1, w2, w3, w4, w5, w6, w7;
  {
    const int4* wsrc = (const int4*)(wih2 + (size_t)g * 128);
    LDW(w0, 0);  LDW(w1, 4);  LDW(w2, 8);  LDW(w3, 12);
    LDW(w4, 16); LDW(w5, 20); LDW(w6, 24); LDW(w7, 28);
  }

  for (int r = 0; r < 64; ++r) {
    const int row = row0 + r;
    const int4* hls = (const int4*)(in16 + (size_t)row * NIN);
    float a0 = 0.f, a1 = 0.f, a2 = 0.f, a3 = 0.f;
    DOT16(w0, 0);  DOT16(w1, 4);  DOT16(w2, 8);  DOT16(w3, 12);
    DOT16(w4, 16); DOT16(w5, 20); DOT16(w6, 24); DOT16(w7, 28);
    xp_out[(size_t)row * NG + g] = (a0 + a1) + (a2 + a3) + bg;
  }
}

// ---------------- recurrence: one block (768 thr, 12 waves) per batch ----------------
// R8 theory: per-step LDS h-broadcast (768 thr x 512 B = 384 KB delivered/step,
// 384 ds_read_b128) is the ~3000-cyc/step floor. h is wave-uniform -> move it to
// SGPRs: tiny global double-buffer (L2-resident), s_load_dwordx16 per wave (one
// copy per WAVE, not per LANE), fdot2 takes the SGPR as src0. Coherence: h stores
// are write-through to this CU's L2; __syncthreads drains vmcnt before s_barrier;
// s_dcache_inv each step forces K$ refill from L2. Math order identical to R7.
struct SMemG {
  float mv[NG];
  char  pad[86016 - NG * 4];   // occupancy clamp: 1 block/CU (as R7)
};
static_assert(sizeof(SMemG) == 86016, "LDS clamp size");

__global__
__attribute__((amdgpu_flat_work_group_size(768, 768), amdgpu_waves_per_eu(3, 3)))
void gru_kernel(const float* __restrict__ xp,
                const half2_t* __restrict__ whh2g,
                _Float16* __restrict__ hglob,
                float* __restrict__ out) {
  const int b = blockIdx.x;
  const int g = threadIdx.x;      // gate-row 0..767

  int16v w0, w1, w2, w3, w4, w5, w6, w7;
  {
    const int4* wsrc = (const int4*)(whh2g + (size_t)g * 128);
    LDW(w0, 0);  LDW(w1, 4);  LDW(w2, 8);  LDW(w3, 12);
    LDW(w4, 16); LDW(w5, 20); LDW(w6, 24); LDW(w7, 28);
  }

  __shared__ SMemG sm;
  {
    unsigned lp = (unsigned)(uintptr_t)&sm.pad[0];
    asm volatile("" :: "v"(lp));
  }

  // per-batch h region: 2 buffers x 256 f16 = 1024 B, 1024B-aligned
  _Float16* hsb = hglob + ((size_t)b << 9);
  const uint64_t hbase = (uint64_t)(uintptr_t)hsb;   // bit9 == 0 by alignment

  if (g < 128) ((int*)hsb)[g] = 0;   // zero buffer 0 (t=0 reads it)

  const float* xq = xp + (size_t)b * NG + g;
  float xr_c = 0.f, xz_c = 0.f, xn_c = 0.f;
  if (g < NH) { xr_c = xq[0]; xz_c = xq[NH]; xn_c = xq[2 * NH]; }
  xq += (size_t)BATCH * NG;
  float* op = out + (size_t)b * NH + g;

  float h = 0.f;
  __syncthreads();   // emits vmcnt(0): zero-init committed to L2

  for (int t = 0; t < S_LEN; ++t) {
    // K$ may hold stale h lines from step t-2's loads of this buffer
    asm volatile("s_dcache_inv" ::: "memory");

    // prefetch xp row t+1 (t=2047 overruns into in16 region: valid, unused)
    float xr_n = 0.f, xz_n = 0.f, xn_n = 0.f;
    if (g < NH) { xr_n = xq[0]; xz_n = xq[NH]; xn_n = xq[2 * NH]; }

    const uint64_t hb = hbase | (uint64_t)((t & 1) << 9);
    int16v s0, s1, s2, s3, s4, s5, s6, s7;
    float a0 = 0.f, a1 = 0.f, a2 = 0.f, a3 = 0.f;

    // pipelined 3/2/2/1: peak 80 h-SGPRs live (budget ~102); waits 2-4 hide
    // under the 32-48 fdot2 of the preceding chunk group
    SLOAD(s0, hb, "0x0"); SLOAD(s1, hb, "0x40"); SLOAD(s2, hb, "0x80");
    SWAIT3(s0, s1, s2);
    SLOAD(s3, hb, "0xc0"); SLOAD(s4, hb, "0x100");
    DOTS(s0, w0); DOTS(s1, w1); DOTS(s2, w2);
    SWAIT2(s3, s4);
    SLOAD(s5, hb, "0x140"); SLOAD(s6, hb, "0x180");
    DOTS(s3, w3); DOTS(s4, w4);
    SWAIT2(s5, s6);
    SLOAD(s7, hb, "0x1c0");
    DOTS(s5, w5); DOTS(s6, w6);
    SWAIT1(s7);
    DOTS(s7, w7);

    sm.mv[g] = (a0 + a1) + (a2 + a3);
    __syncthreads();

    if (g < NH) {
      float mvr = sm.mv[g], mvz = sm.mv[NH + g], mvn = sm.mv[2 * NH + g];
      float r = sigmoid_fast(xr_c + mvr);
      float z = sigmoid_fast(xz_c + mvz);
      float n = tanh_fast(xn_c + mvn + r * mvn);  // torch quirk: mv_n enters twice
      h = z * (h - n) + n;
      op[0] = h;
      hsb[(((t + 1) & 1) << 8) + g] = (_Float16)h;  // other buffer, write-through to L2
    }
    __syncthreads();   // emits vmcnt(0): h stores committed before next s_loads

    xr_c = xr_n; xz_c = xz_n; xn_c = xn_n;
    xq += (size_t)BATCH * NG;
    op += (size_t)BATCH * NH;
  }

  if (g < NH) out[(size_t)S_LEN * BATCH * NH + (size_t)b * NH + g] = h;
}

extern "C" void kernel_launch(void* const* d_in, const int* in_sizes, int n_in,
                              void* d_out, int out_size, void* d_ws, size_t ws_size,
                              hipStream_t stream) {
  const float* input = (const float*)d_in[0];
  const float* W_ih  = (const float*)d_in[1];
  const float* W_hh  = (const float*)d_in[2];
  const float* b_ih  = (const float*)d_in[3];
  const float* b_hh  = (const float*)d_in[4];
  float* out = (float*)d_out;

  const size_t SB = (size_t)S_LEN * BATCH;           // 65536
  const size_t xp_b   = SB * NG * 4;                 // 192 MiB
  const size_t in16_b = SB * NIN * 2;                // 32 MiB
  const size_t w_b    = (size_t)128 * NG * 4;        // 384 KiB each

  char* p = (char*)d_ws;
  float*    xp    = (float*)p;                p += xp_b;
  _Float16* in16  = (_Float16*)p;             p += in16_b;
  half2_t*  whh2g = (half2_t*)p;              p += w_b;
  half2_t*  wih2  = (half2_t*)p;              p += w_b;
  float*    bias  = (float*)p;                p += (size_t)NG * 4;
  uintptr_t hp = (((uintptr_t)p) + 1023) & ~(uintptr_t)1023;
  _Float16* hglob = (_Float16*)hp;            // 32 KiB h double-buffers

  prep_in_kernel<<<8192, 256, 0, stream>>>(input, in16);
  prep_w_kernel<<<(2 * 128 * NG + NG + 255) / 256, 256, 0, stream>>>(W_ih, W_hh, b_ih, b_hh,
                                                                     whh2g, wih2, bias);
  xproj_kernel<<<1024, 768, 0, stream>>>(in16, wih2, bias, xp);
  gru_kernel<<<BATCH, 768, 0, stream>>>(xp, whh2g, hglob, out);
  (void)out_size; (void)n_in; (void)in_sizes; (void)ws_size;
}

// Round 2
// 2679.440 us; speedup vs baseline: 1.0551x; 1.0551x over previous
//
#include <hip/hip_runtime.h>
#include <stdint.h>
#include <stddef.h>

#define S_LEN 2048
#define BATCH 32
#define NIN   256
#define NH    256
#define NG    768   // 3*NH

typedef _Float16 half2_t __attribute__((ext_vector_type(2)));
typedef _Float16 half8_t __attribute__((ext_vector_type(8)));
typedef int      int16v  __attribute__((ext_vector_type(16)));

#if __has_builtin(__builtin_amdgcn_exp2f)
#define EXP2F(x) __builtin_amdgcn_exp2f(x)
#else
#define EXP2F(x) exp2f(x)
#endif

static __device__ __forceinline__ float fdot2(half2_t a, half2_t b, float c) {
  return __builtin_amdgcn_fdot2(a, b, c, false);
}
static __device__ __forceinline__ half2_t pack2(float lo, float hi) {
  half2_t r; r[0] = (_Float16)lo; r[1] = (_Float16)hi; return r;
}
static __device__ __forceinline__ float sigmoid_fast(float x) {
  float e = EXP2F(-1.44269504088896340736f * x);
  return 1.0f / (1.0f + e);
}
static __device__ __forceinline__ float tanh_fast(float x) {
  float e = EXP2F(2.88539008177792681472f * x);
  return 1.0f - 2.0f / (1.0f + e);
}

// lane-pair sum via DPP quad_perm [1,0,3,2] (register-file exchange, no LDS):
// lane0 gets v0+v1, lane1 gets v1+v0 -> bit-identical across the pair.
static __device__ __forceinline__ float pair_sum(float v) {
  int y = __builtin_amdgcn_mov_dpp(__builtin_bit_cast(int, v), 0xB1, 0xF, 0xF, true);
  return v + __builtin_bit_cast(float, y);
}

// bit-cast helpers: element extracts use LITERAL indices -> pure SSA, no allocas
#define BH(x)    __builtin_bit_cast(half2_t, (x))
#define BW(W, e) __builtin_bit_cast(half2_t, (int)((W)[e]))

// ---- xproj path (unchanged) ----
#define DOT16(W, i0) do {                                                     \
    int4 q0 = hls[(i0) + 0], q1 = hls[(i0) + 1];                              \
    int4 q2 = hls[(i0) + 2], q3 = hls[(i0) + 3];                              \
    a0 = fdot2(BH(q0.x), BW(W, 0),  a0); a1 = fdot2(BH(q0.y), BW(W, 1),  a1);\
    a2 = fdot2(BH(q0.z), BW(W, 2),  a2); a3 = fdot2(BH(q0.w), BW(W, 3),  a3);\
    a0 = fdot2(BH(q1.x), BW(W, 4),  a0); a1 = fdot2(BH(q1.y), BW(W, 5),  a1);\
    a2 = fdot2(BH(q1.z), BW(W, 6),  a2); a3 = fdot2(BH(q1.w), BW(W, 7),  a3);\
    a0 = fdot2(BH(q2.x), BW(W, 8),  a0); a1 = fdot2(BH(q2.y), BW(W, 9),  a1);\
    a2 = fdot2(BH(q2.z), BW(W, 10), a2); a3 = fdot2(BH(q2.w), BW(W, 11), a3);\
    a0 = fdot2(BH(q3.x), BW(W, 12), a0); a1 = fdot2(BH(q3.y), BW(W, 13), a1);\
    a2 = fdot2(BH(q3.z), BW(W, 14), a2); a3 = fdot2(BH(q3.w), BW(W, 15), a3);\
  } while (0)

// ---- gru path: 16 h-elems (2 int4) against 3 gate weight slices, gates
// interleaved so same-accumulator reuse distance is 6 instrs (no VALU stalls).
#define DOT24(q0, q1, WR, WZ, WN, o) do {                                               \
  ar0 = fdot2(BH(q0.x), BW(WR,(o)+0), ar0); az0 = fdot2(BH(q0.x), BW(WZ,(o)+0), az0);  \
  an0 = fdot2(BH(q0.x), BW(WN,(o)+0), an0);                                            \
  ar1 = fdot2(BH(q0.y), BW(WR,(o)+1), ar1); az1 = fdot2(BH(q0.y), BW(WZ,(o)+1), az1);  \
  an1 = fdot2(BH(q0.y), BW(WN,(o)+1), an1);                                            \
  ar0 = fdot2(BH(q0.z), BW(WR,(o)+2), ar0); az0 = fdot2(BH(q0.z), BW(WZ,(o)+2), az0);  \
  an0 = fdot2(BH(q0.z), BW(WN,(o)+2), an0);                                            \
  ar1 = fdot2(BH(q0.w), BW(WR,(o)+3), ar1); az1 = fdot2(BH(q0.w), BW(WZ,(o)+3), az1);  \
  an1 = fdot2(BH(q0.w), BW(WN,(o)+3), an1);                                            \
  ar0 = fdot2(BH(q1.x), BW(WR,(o)+4), ar0); az0 = fdot2(BH(q1.x), BW(WZ,(o)+4), az0);  \
  an0 = fdot2(BH(q1.x), BW(WN,(o)+4), an0);                                            \
  ar1 = fdot2(BH(q1.y), BW(WR,(o)+5), ar1); az1 = fdot2(BH(q1.y), BW(WZ,(o)+5), az1);  \
  an1 = fdot2(BH(q1.y), BW(WN,(o)+5), an1);                                            \
  ar0 = fdot2(BH(q1.z), BW(WR,(o)+6), ar0); az0 = fdot2(BH(q1.z), BW(WZ,(o)+6), az0);  \
  an0 = fdot2(BH(q1.z), BW(WN,(o)+6), an0);                                            \
  ar1 = fdot2(BH(q1.w), BW(WR,(o)+7), ar1); az1 = fdot2(BH(q1.w), BW(WZ,(o)+7), az1);  \
  an1 = fdot2(BH(q1.w), BW(WN,(o)+7), an1);                                            \
} while (0)

#define LDW(W, o) do {                                                        \
    int4 q0 = wsrc[(o) + 0], q1 = wsrc[(o) + 1];                              \
    int4 q2 = wsrc[(o) + 2], q3 = wsrc[(o) + 3];                              \
    W = (int16v){q0.x, q0.y, q0.z, q0.w, q1.x, q1.y, q1.z, q1.w,              \
                 q2.x, q2.y, q2.z, q2.w, q3.x, q3.y, q3.z, q3.w};             \
  } while (0)

// ---------------- prep: input f32 -> f16 ----------------
__global__ __launch_bounds__(256) void prep_in_kernel(const float* __restrict__ in,
                                                      _Float16* __restrict__ in16) {
  size_t v = (size_t)blockIdx.x * 256 + threadIdx.x;
  const float4* p4 = (const float4*)in;
  float4 a = p4[v * 2 + 0];
  float4 b = p4[v * 2 + 1];
  half8_t o;
  o[0] = (_Float16)a.x; o[1] = (_Float16)a.y; o[2] = (_Float16)a.z; o[3] = (_Float16)a.w;
  o[4] = (_Float16)b.x; o[5] = (_Float16)b.y; o[6] = (_Float16)b.z; o[7] = (_Float16)b.w;
  ((half8_t*)in16)[v] = o;
}

// ---------------- prep: weights pack to f16 pairs + bias ----------------
// whh3 layout for the K-split recurrence: thread tid = j*2+c owns 192
// contiguous dwords: [j][c][gate][kk], kk in [0,64): half2 of W_hh row
// (gate*256+j), cols [128c + 2kk, +1].
__global__ __launch_bounds__(256) void prep_w_kernel(const float* __restrict__ W_ih,
                                                     const float* __restrict__ W_hh,
                                                     const float* __restrict__ b_ih,
                                                     const float* __restrict__ b_hh,
                                                     half2_t* __restrict__ whh3,
                                                     half2_t* __restrict__ wih2,
                                                     float* __restrict__ bias) {
  int idx = blockIdx.x * 256 + threadIdx.x;
  if (idx < 128 * NG) {
    int kk = idx & 63;
    int r1 = idx >> 6;
    int gate = r1 % 3;
    int r2 = r1 / 3;
    int cc = r2 & 1;
    int jj = r2 >> 1;
    int row = gate * NH + jj;
    int col = cc * 128 + 2 * kk;
    whh3[idx] = pack2(W_hh[(size_t)row * NH + col], W_hh[(size_t)row * NH + col + 1]);
  } else if (idx < 2 * 128 * NG) {
    int i2 = idx - 128 * NG;
    int g = i2 >> 7, kk = i2 & 127;
    wih2[(size_t)g * 128 + kk] = pack2(W_ih[(size_t)g * NIN + 2 * kk], W_ih[(size_t)g * NIN + 2 * kk + 1]);
  } else if (idx < 2 * 128 * NG + NG) {
    int g = idx - 2 * 128 * NG;
    bias[g] = b_ih[g] + b_hh[g];
  }
}

// ---------------- x_proj GEMM (unchanged) ----------------
__global__
__attribute__((amdgpu_flat_work_group_size(768, 768), amdgpu_waves_per_eu(3, 3)))
void xproj_kernel(const _Float16* __restrict__ in16,
                  const half2_t* __restrict__ wih2,
                  const float* __restrict__ bias,
                  float* __restrict__ xp_out) {
  __shared__ char occ_pad[86016];
  {
    unsigned lp = (unsigned)(uintptr_t)&occ_pad[0];
    asm volatile("" :: "v"(lp));
  }
  const int g = threadIdx.x;
  const int row0 = blockIdx.x * 64;
  const float bg = bias[g];

  int16v w0, w1, w2, w3, w4, w5, w6, w7;
  {
    const int4* wsrc = (const int4*)(wih2 + (size_t)g * 128);
    LDW(w0, 0);  LDW(w1, 4);  LDW(w2, 8);  LDW(w3, 12);
    LDW(w4, 16); LDW(w5, 20); LDW(w6, 24); LDW(w7, 28);
  }

  for (int r = 0; r < 64; ++r) {
    const int row = row0 + r;
    const int4* hls = (const int4*)(in16 + (size_t)row * NIN);
    float a0 = 0.f, a1 = 0.f, a2 = 0.f, a3 = 0.f;
    DOT16(w0, 0);  DOT16(w1, 4);  DOT16(w2, 8);  DOT16(w3, 12);
    DOT16(w4, 16); DOT16(w5, 20); DOT16(w6, 24); DOT16(w7, 28);
    xp_out[(size_t)row * NG + g] = (a0 + a1) + (a2 + a3) + bg;
  }
}

// ---------------- recurrence: K-split, one barrier per step ----------------
// R9: R8 falsified "LDS broadcast BW is the floor" (SGPR broadcast = neutral).
// Shared floor of R7/R8: 2 barriers/step with full vmcnt(0) drains + the mv
// LDS round-trip (write mv / barrier / read mv / elementwise / write h /
// barrier). This version removes the mv exchange entirely: 512 threads,
// thread (j = tid>>1, c = tid&1) computes ALL 3 gate rows j over K-half c
// (192 fdot2, 192 weight dwords; 8 waves -> 2/SIMD @ <=256 VGPR). Cross-c
// reduction = one DPP quad-perm butterfly (no LDS, no barrier). Elementwise
// computed redundantly on both pair lanes (bit-identical). One raw s_barrier
// per step with lgkmcnt(0) only -- out-stores and xp prefetches stay in
// flight across steps (no vmcnt drain). Double-buffered LDS h keeps the
// single barrier race-free; 272 B chunk stride puts the pair's two read
// addresses on distinct banks.
__global__
__attribute__((amdgpu_flat_work_group_size(512, 512), amdgpu_waves_per_eu(2, 2)))
void gru_kernel(const float* __restrict__ xp,
                const half2_t* __restrict__ whh3,
                float* __restrict__ out) {
  const int b   = blockIdx.x;
  const int tid = threadIdx.x;
  const int j   = tid >> 1;      // h row 0..255
  const int c   = tid & 1;       // K-half

  int16v wr0, wr1, wr2, wr3, wz0, wz1, wz2, wz3, wn0, wn1, wn2, wn3;
  {
    const int4* wsrc = (const int4*)(whh3 + (size_t)tid * 192);
    LDW(wr0, 0);  LDW(wr1, 4);  LDW(wr2, 8);  LDW(wr3, 12);
    LDW(wz0, 16); LDW(wz1, 20); LDW(wz2, 24); LDW(wz3, 28);
    LDW(wn0, 32); LDW(wn1, 36); LDW(wn2, 40); LDW(wn3, 44);
  }

  // 2 buffers x (2 chunks x 272 B) ; chunk holds 128 f16 (256 B) + 16 B pad
  __shared__ __attribute__((aligned(16))) char smh[1088];
  if (tid < 272) ((int*)smh)[tid] = 0;   // zero both buffers

  const float* xq = xp + (size_t)b * NG + j;
  float xr_c = xq[0], xz_c = xq[NH], xn_c = xq[2 * NH];
  xq += (size_t)BATCH * NG;
  float* op = out + (size_t)b * NH + j;

  const int wofs = (j >> 7) * 272 + (j & 127) * 2;   // h write offset in buffer

  float h = 0.f;
  __syncthreads();

  for (int t = 0; t < S_LEN; ++t) {
    // prefetch xp row t+1 (t=2047 overruns into in16 region: valid, unused)
    float xr_n = xq[0], xz_n = xq[NH], xn_n = xq[2 * NH];

    const char* hb = smh + (t & 1) * 544 + c * 272;
    float ar0 = 0.f, ar1 = 0.f, az0 = 0.f, az1 = 0.f, an0 = 0.f, an1 = 0.f;
    int4 q0, q1;
    q0 = *(const int4*)(hb +   0); q1 = *(const int4*)(hb +  16);
    DOT24(q0, q1, wr0, wz0, wn0, 0);
    q0 = *(const int4*)(hb +  32); q1 = *(const int4*)(hb +  48);
    DOT24(q0, q1, wr0, wz0, wn0, 8);
    q0 = *(const int4*)(hb +  64); q1 = *(const int4*)(hb +  80);
    DOT24(q0, q1, wr1, wz1, wn1, 0);
    q0 = *(const int4*)(hb +  96); q1 = *(const int4*)(hb + 112);
    DOT24(q0, q1, wr1, wz1, wn1, 8);
    q0 = *(const int4*)(hb + 128); q1 = *(const int4*)(hb + 144);
    DOT24(q0, q1, wr2, wz2, wn2, 0);
    q0 = *(const int4*)(hb + 160); q1 = *(const int4*)(hb + 176);
    DOT24(q0, q1, wr2, wz2, wn2, 8);
    q0 = *(const int4*)(hb + 192); q1 = *(const int4*)(hb + 208);
    DOT24(q0, q1, wr3, wz3, wn3, 0);
    q0 = *(const int4*)(hb + 224); q1 = *(const int4*)(hb + 240);
    DOT24(q0, q1, wr3, wz3, wn3, 8);

    float mvr = pair_sum(ar0 + ar1);
    float mvz = pair_sum(az0 + az1);
    float mvn = pair_sum(an0 + an1);

    float r = sigmoid_fast(xr_c + mvr);
    float z = sigmoid_fast(xz_c + mvz);
    float n = tanh_fast(xn_c + mvn + r * mvn);  // torch quirk: mv_n enters twice
    h = z * (h - n) + n;

    if (c == 0) {
      op[0] = h;
      *(_Float16*)(smh + (((t + 1) & 1) * 544) + wofs) = (_Float16)h;
    }
    // h ds_write visible to all waves; no vmcnt drain (stores float freely)
    asm volatile("s_waitcnt lgkmcnt(0)\n\ts_barrier" ::: "memory");

    xr_c = xr_n; xz_c = xz_n; xn_c = xn_n;
    xq += (size_t)BATCH * NG;
    op += (size_t)BATCH * NH;
  }

  if (c == 0) out[(size_t)S_LEN * BATCH * NH + (size_t)b * NH + j] = h;
}

extern "C" void kernel_launch(void* const* d_in, const int* in_sizes, int n_in,
                              void* d_out, int out_size, void* d_ws, size_t ws_size,
                              hipStream_t stream) {
  const float* input = (const float*)d_in[0];
  const float* W_ih  = (const float*)d_in[1];
  const float* W_hh  = (const float*)d_in[2];
  const float* b_ih  = (const float*)d_in[3];
  const float* b_hh  = (const float*)d_in[4];
  float* out = (float*)d_out;

  const size_t SB = (size_t)S_LEN * BATCH;           // 65536
  const size_t xp_b   = SB * NG * 4;                 // 192 MiB
  const size_t in16_b = SB * NIN * 2;                // 32 MiB
  const size_t w_b    = (size_t)128 * NG * 4;        // 384 KiB each

  char* p = (char*)d_ws;
  float*    xp    = (float*)p;                p += xp_b;
  _Float16* in16  = (_Float16*)p;             p += in16_b;
  half2_t*  whh3  = (half2_t*)p;              p += w_b;
  half2_t*  wih2  = (half2_t*)p;              p += w_b;
  float*    bias  = (float*)p;

  prep_in_kernel<<<8192, 256, 0, stream>>>(input, in16);
  prep_w_kernel<<<(2 * 128 * NG + NG + 255) / 256, 256, 0, stream>>>(W_ih, W_hh, b_ih, b_hh,
                                                                     whh3, wih2, bias);
  xproj_kernel<<<1024, 768, 0, stream>>>(in16, wih2, bias, xp);
  gru_kernel<<<BATCH, 512, 0, stream>>>(xp, whh3, out);
  (void)out_size; (void)n_in; (void)in_sizes; (void)ws_size;
}